// Round 7
// baseline (10567.531 us; speedup 1.0000x reference)
//
#include <hip/hip_runtime.h>
#include <math.h>

// Trajectory2seq persistent kernel, round 7 = round 3 (proven, 10.28ms) with
// ONE change: stage_panel batches its coherent loads.
// Round-3 measured 3.8 GB/s/CU staging == exactly ONE outstanding MALL RTT
// per wave (compiler serializes waitcnt after each __hip_atomic_load):
// 8 waves x 512B / 800ns = 5 GB/s/CU. Fix: stage_panel issues 8x
// global_load_dwordx4 sc0 sc1 in a single asm block with the s_waitcnt
// INSIDE the asm (consumers are data-dependent on outputs -> no hoist
// hazard; round-2 lesson). 8 outstanding/wave -> ~8x staging rate.
// Everything else (barriers, fc, flush, stores, ws layout) is byte-identical
// to round 3, so failure uniquely indicts the asm-load primitive and a pass
// validates it. Rounds 4-6's XCD-local exchange is parked: r5/r6 failed
// identically despite disjoint fixes -> unresolved poison in that machinery.

#define Bb   256
#define Tt   128
#define Hh   1024
#define Vv   64
#define LIN  457
#define ML   64
#define NKB_H  32   // K=1024 -> 32 k-blocks of 32
#define NKB_X  15   // K=480  -> 15 k-blocks
#define XST  496    // LDS x row stride (bank spread, 16B aligned)
#define NBLK 256    // persistent grid: 1 block per CU
#define NTHR 512    // 8 waves per block

typedef __bf16 bf16;
typedef __bf16 bf16x8 __attribute__((ext_vector_type(8)));
typedef float  f32x4  __attribute__((ext_vector_type(4)));
typedef unsigned int u32x4 __attribute__((ext_vector_type(4)));
typedef unsigned long long ull;

static __device__ __forceinline__ float bf2f(bf16 x) {
    unsigned short u = __builtin_bit_cast(unsigned short, x);
    unsigned int w = ((unsigned int)u) << 16;
    return __builtin_bit_cast(float, w);
}
static __device__ __forceinline__ unsigned short f2bfbits(float f) {
    unsigned int u = __builtin_bit_cast(unsigned int, f);
    u = u + 0x7FFFu + ((u >> 16) & 1u);   // RNE (finite only)
    return (unsigned short)(u >> 16);
}
static __device__ __forceinline__ bf16 f2bf(float f) {
    return __builtin_bit_cast(bf16, f2bfbits(f));
}
static __device__ __forceinline__ float ubf(unsigned u) {
    return __builtin_bit_cast(float, u << 16);
}

#define MFMA(a, b, c) __builtin_amdgcn_mfma_f32_16x16x32_bf16((a), (b), (c), 0, 0, 0)

// ---- coherent (agent-scope, LLC) accesses; compiler-managed waitcnts ------
static __device__ __forceinline__ ull ld_c64(const void* p) {
    return __hip_atomic_load((const ull*)p, __ATOMIC_RELAXED,
                             __HIP_MEMORY_SCOPE_AGENT);
}
static __device__ __forceinline__ void st_c64(void* p, ull v) {
    __hip_atomic_store((ull*)p, v, __ATOMIC_RELAXED, __HIP_MEMORY_SCOPE_AGENT);
}
static __device__ __forceinline__ unsigned ld_c32(const void* p) {
    return __hip_atomic_load((const unsigned*)p, __ATOMIC_RELAXED,
                             __HIP_MEMORY_SCOPE_AGENT);
}
static __device__ __forceinline__ void st_c32(void* p, unsigned v) {
    __hip_atomic_store((unsigned*)p, v, __ATOMIC_RELAXED,
                       __HIP_MEMORY_SCOPE_AGENT);
}

// ---- one-time: fp32 W[N][K] -> packed hi/lo fragments ---------------------
__global__ __launch_bounds__(256) void pack_w_k(const float* __restrict__ src,
                                                bf16* __restrict__ hp,
                                                bf16* __restrict__ lp,
                                                int nkb, int src_ld, int kmax) {
    const int tid = blockIdx.x * 256 + threadIdx.x;
    const int lane = tid & 63;
    const int kb = (tid >> 6) % nkb;
    const int nt = tid / (64 * nkb);
    if (nt >= 64) return;
    const int row = nt * 16 + (lane & 15);
    const int k0 = kb * 32 + (lane >> 4) * 8;
    const float* s = src + (size_t)row * src_ld;
    bf16x8 h8, l8;
#pragma unroll
    for (int j = 0; j < 8; j++) {
        float v = (k0 + j < kmax) ? s[k0 + j] : 0.f;
        bf16 h = f2bf(v);
        h8[j] = h;
        l8[j] = f2bf(v - bf2f(h));
    }
    *(bf16x8*)(hp + (size_t)tid * 8) = h8;
    *(bf16x8*)(lp + (size_t)tid * 8) = l8;
}

// ---- 2-deep-W-prefetch 16x16 gemm, A from LDS, split accumulators ---------
template <int ASTR>
static __device__ __forceinline__ void gemm_lds(
    const bf16* aH, const bf16* aL,
    const bf16* __restrict__ wH, const bf16* __restrict__ wL,
    int n, f32x4* accio) {
    f32x4 accA = *accio;
    f32x4 accB = (f32x4){0.f, 0.f, 0.f, 0.f};
    bf16x8 wh0 = *(const bf16x8*)(wH);
    bf16x8 wl0 = *(const bf16x8*)(wL);
    bf16x8 wh1 = wh0, wl1 = wl0;
    if (n > 1) { wh1 = *(const bf16x8*)(wH + 512); wl1 = *(const bf16x8*)(wL + 512); }
    int i = 0;
    for (; i + 2 <= n; i += 2) {
        bf16x8 a0h = *(const bf16x8*)(aH + (size_t)i * ASTR);
        bf16x8 a0l = *(const bf16x8*)(aL + (size_t)i * ASTR);
        bf16x8 a1h = *(const bf16x8*)(aH + (size_t)(i + 1) * ASTR);
        bf16x8 a1l = *(const bf16x8*)(aL + (size_t)(i + 1) * ASTR);
        bf16x8 cwh0 = wh0, cwl0 = wl0, cwh1 = wh1, cwl1 = wl1;
        if (i + 2 < n) { wh0 = *(const bf16x8*)(wH + (size_t)(i + 2) * 512);
                         wl0 = *(const bf16x8*)(wL + (size_t)(i + 2) * 512); }
        if (i + 3 < n) { wh1 = *(const bf16x8*)(wH + (size_t)(i + 3) * 512);
                         wl1 = *(const bf16x8*)(wL + (size_t)(i + 3) * 512); }
        accA = MFMA(a0h, cwh0, accA);
        accA = MFMA(a0l, cwh0, accA);
        accA = MFMA(a0h, cwl0, accA);
        accB = MFMA(a1h, cwh1, accB);
        accB = MFMA(a1l, cwh1, accB);
        accB = MFMA(a1h, cwl1, accB);
    }
    if (i < n) {
        bf16x8 ah_ = *(const bf16x8*)(aH + (size_t)i * ASTR);
        bf16x8 al_ = *(const bf16x8*)(aL + (size_t)i * ASTR);
        accA = MFMA(ah_, wh0, accA);
        accA = MFMA(al_, wh0, accA);
        accA = MFMA(ah_, wl0, accA);
    }
    *accio = accA + accB;
}

// ---- stage one state panel (32KB hi + 32KB lo) into LDS -------------------
// THE round-7 change: one asm block, 8x dwordx4 sc0 sc1 loads (64B hi + 64B
// lo per thread, contiguous chunks), ONE s_waitcnt vmcnt(0) INSIDE the asm.
// Identity copy global->LDS, so the re-chunking (vs r3's j*4096+tid*8) is
// semantically free. Consumers depend on asm outputs -> no hoist hazard.
static __device__ __forceinline__ void stage_panel(
    const bf16* gh, const bf16* gl, bf16* sh, bf16* sl, int tid) {
    const char* ah = (const char*)gh + (size_t)tid * 64;
    const char* al = (const char*)gl + (size_t)tid * 64;
    u32x4 h0, h1, h2, h3, l0, l1, l2, l3;
    asm volatile(
        "global_load_dwordx4 %0, %8, off sc0 sc1\n\t"
        "global_load_dwordx4 %1, %8, off offset:16 sc0 sc1\n\t"
        "global_load_dwordx4 %2, %8, off offset:32 sc0 sc1\n\t"
        "global_load_dwordx4 %3, %8, off offset:48 sc0 sc1\n\t"
        "global_load_dwordx4 %4, %9, off sc0 sc1\n\t"
        "global_load_dwordx4 %5, %9, off offset:16 sc0 sc1\n\t"
        "global_load_dwordx4 %6, %9, off offset:32 sc0 sc1\n\t"
        "global_load_dwordx4 %7, %9, off offset:48 sc0 sc1\n\t"
        "s_waitcnt vmcnt(0)"
        : "=&v"(h0), "=&v"(h1), "=&v"(h2), "=&v"(h3),
          "=&v"(l0), "=&v"(l1), "=&v"(l2), "=&v"(l3)
        : "v"(ah), "v"(al)
        : "memory");
    char* dh = (char*)sh + (size_t)tid * 64;
    char* dl = (char*)sl + (size_t)tid * 64;
    *(u32x4*)(dh +  0) = h0; *(u32x4*)(dh + 16) = h1;
    *(u32x4*)(dh + 32) = h2; *(u32x4*)(dh + 48) = h3;
    *(u32x4*)(dl +  0) = l0; *(u32x4*)(dl + 16) = l1;
    *(u32x4*)(dl + 32) = l2; *(u32x4*)(dl + 48) = l3;
}

// ---- phase output: role0 writes tanh'd hi/lo into LDS stage ---------------
static __device__ __forceinline__ void emit_tile(
    f32x4 acc, bool writer, int tile, int lm, int quad,
    unsigned short* sst_h, unsigned short* sst_l) {
    if (writer) {
        const int base = tile * 256 + (lm >> 3) * 128 + quad * 32 + (lm & 7);
#pragma unroll
        for (int r = 0; r < 4; r++) {
            float h = tanhf(acc[r]);
            unsigned short hb = f2bfbits(h);
            sst_h[base + r * 8] = hb;
            sst_l[base + r * 8] = f2bfbits(h - ubf((unsigned)hb));
        }
    }
    __syncthreads();
}

// ---- all threads: flush 4 tiles (contiguous 256-elem chunks) coherently ---
static __device__ __forceinline__ void flush_tiles(
    const unsigned short* sst_h, const unsigned short* sst_l,
    bf16* ohi, bf16* olo, int mt, int lidx, int tid) {
    const int comp = tid >> 8;           // 0: hi, 1: lo
    const int tile = (tid >> 6) & 3;
    const int q = tid & 63;
    const int nt = lidx * 4 + tile;
    const size_t gb = ((size_t)mt * 32 + (nt >> 1)) * 512
                      + (size_t)(nt & 1) * 256 + q * 4;
    const unsigned short* s = comp ? sst_l : sst_h;
    ull v = *(const ull*)(s + tile * 256 + q * 4);
    st_c64((comp ? olo : ohi) + gb, v);
}

// ------- one-time: EP[v][n] = emb[v] @ dec_Wih0^T + dec_b0 (fp64->fp32) ----
__global__ __launch_bounds__(256) void dec_pre_k(const float* __restrict__ emb,
                                                 const float* __restrict__ W,
                                                 const float* __restrict__ b,
                                                 float* __restrict__ EP) {
    const int n = blockIdx.x * 256 + threadIdx.x;
    const int v = blockIdx.y * 4;
    double acc[4];
    const double bv = (double)b[n];
    acc[0] = acc[1] = acc[2] = acc[3] = bv;
    const float* wr = W + (size_t)n * Hh;
#pragma unroll 4
    for (int k = 0; k < Hh; k++) {
        double wv = (double)wr[k];
        acc[0] = fma((double)emb[(size_t)(v + 0) * Hh + k], wv, acc[0]);
        acc[1] = fma((double)emb[(size_t)(v + 1) * Hh + k], wv, acc[1]);
        acc[2] = fma((double)emb[(size_t)(v + 2) * Hh + k], wv, acc[2]);
        acc[3] = fma((double)emb[(size_t)(v + 3) * Hh + k], wv, acc[3]);
    }
#pragma unroll
    for (int r = 0; r < 4; r++) EP[(size_t)(v + r) * Hh + n] = (float)acc[r];
}

// --------------------------- persistent kernel -----------------------------
struct Params {
    const float* x;
    const bf16 *w0h, *w0l;
    const bf16 *eU0h, *eU0l, *eW1h, *eW1l, *eU1h, *eU1l;
    const bf16 *dU0h, *dU0l, *dW1h, *dW1l, *dU1h, *dU1l;
    const float *eb0, *eb1, *db1;
    const float *EP, *fcw, *fcb;
    float* out;
    int* tok;
    bf16* h0[2][2];   // [pingpong][hi/lo]
    bf16* h1[2][2];
    unsigned* flags;  // [256] monotonic, 128B-strided
};

// group barrier over the 16 blocks of an mt-group: relaxed atomics, no cache
// maintenance. vmcnt(0)+syncthreads orders all prior coherent stores before
// the flag publication.
static __device__ __forceinline__ void gbar16(unsigned* flags, int mt, int lidx,
                                              unsigned ph) {
    asm volatile("s_waitcnt vmcnt(0)" ::: "memory");
    __syncthreads();
    if (threadIdx.x == 0)
        __hip_atomic_store(flags + (size_t)(mt * 16 + lidx) * 32, ph,
                           __ATOMIC_RELAXED, __HIP_MEMORY_SCOPE_AGENT);
    if (threadIdx.x < 16) {
        while (__hip_atomic_load(flags + (size_t)(mt * 16 + threadIdx.x) * 32,
                                 __ATOMIC_RELAXED, __HIP_MEMORY_SCOPE_AGENT) < ph)
            __builtin_amdgcn_s_sleep(1);
    }
    __syncthreads();
    asm volatile("" ::: "memory");
}

static __device__ __forceinline__ size_t sidx(int b, int k) {
    return ((((size_t)(b >> 4)) * 32 + (k >> 5)) * 64 + ((k >> 3) & 3) * 16
            + (b & 15)) * 8 + (k & 7);
}

// layer-1 step (encoder L1 / decoder L1)
static __device__ __forceinline__ void phase_rnn2(
    const bf16* xh_g, const bf16* xl_g,
    const bf16* __restrict__ wih, const bf16* __restrict__ wil,
    const bf16* hh_g, const bf16* hl_g,
    const bf16* __restrict__ whh, const bf16* __restrict__ whl,
    const float* bias, bf16* ohi, bf16* olo,
    bf16* smA_h, bf16* smA_l, bf16* smB_h, bf16* smB_l,
    float* red, unsigned short* sst_h, unsigned short* sst_l,
    int mt, int lidx, int nt, int tile, int role,
    int lane, int lm, int quad, int tid) {
    stage_panel(xh_g + (size_t)mt * 16384, xl_g + (size_t)mt * 16384,
                smA_h, smA_l, tid);
    stage_panel(hh_g + (size_t)mt * 16384, hl_g + (size_t)mt * 16384,
                smB_h, smB_l, tid);
    __syncthreads();
    f32x4 acc = (f32x4){0.f, 0.f, 0.f, 0.f};
    if (role == 0) {
        float bv = bias[nt * 16 + lm];
        acc = (f32x4){bv, bv, bv, bv};
        gemm_lds<512>(smA_h + lane * 8, smA_l + lane * 8,
                      wih + (size_t)nt * NKB_H * 512 + lane * 8,
                      wil + (size_t)nt * NKB_H * 512 + lane * 8, NKB_H, &acc);
    } else {
        gemm_lds<512>(smB_h + lane * 8, smB_l + lane * 8,
                      whh + (size_t)nt * NKB_H * 512 + lane * 8,
                      whl + (size_t)nt * NKB_H * 512 + lane * 8, NKB_H, &acc);
        red[tile * 256 + lane * 4 + 0] = acc[0];
        red[tile * 256 + lane * 4 + 1] = acc[1];
        red[tile * 256 + lane * 4 + 2] = acc[2];
        red[tile * 256 + lane * 4 + 3] = acc[3];
    }
    __syncthreads();
    if (role == 0) {
#pragma unroll
        for (int r = 0; r < 4; r++) acc[r] += red[tile * 256 + lane * 4 + r];
    }
    emit_tile(acc, role == 0, tile, lm, quad, sst_h, sst_l);
    flush_tiles(sst_h, sst_l, ohi, olo, mt, lidx, tid);
}

#define SM_BYTES 139264

__global__ __launch_bounds__(NTHR, 2) void persist_k(Params p) {
    __shared__ __align__(16) char smem[SM_BYTES];
    bf16* const smA_h = (bf16*)smem;                    // 16384 elems (32KB)
    bf16* const smA_l = (bf16*)smem + 16384;
    bf16* const smB_h = (bf16*)smem + 32768;
    bf16* const smB_l = (bf16*)smem + 49152;
    float* const red  = (float*)(smem + 131072);        // 4KB
    unsigned short* const sst_h = (unsigned short*)(smem + 135168);  // 2KB
    unsigned short* const sst_l = (unsigned short*)(smem + 137216);  // 2KB
    double* const hrow = (double*)smem;                 // fc overlay [4][1024]
    double* const dred = (double*)(smem + 131072);      // fc overlay [4][64]
    bf16* const xsh = (bf16*)smem + 32768;              // enc L0 x overlay
    bf16* const xsl = xsh + 16 * XST;

    const int tid = threadIdx.x;
    const int blk = blockIdx.x;
    const int lane = tid & 63, wave = tid >> 6;
    const int lm = lane & 15, quad = lane >> 4;
    const int tile = wave >> 1, role = wave & 1;   // 4 tiles x 2 roles
    const int mt = blk >> 4;                       // group id 0..15
    const int lidx = blk & 15;                     // block-in-group
    const int nt = lidx * 4 + tile;                // 0..63
    unsigned ph = 0;

    // ------------------------------ encoder -------------------------------
    for (int t = 0; t < Tt; t++) {
        const int in = t & 1, op = in ^ 1;
        // ---- enc L0 ----
        {
            for (int idx = tid; idx < 16 * XST; idx += NTHR) {
                int row = idx / XST, col = idx - row * XST;
                float v = 0.f;
                if (col < LIN)
                    v = __builtin_nontemporal_load(
                        &p.x[((size_t)(mt * 16 + row) * Tt + t) * LIN + col]);
                bf16 h = f2bf(v);
                xsh[idx] = h;
                xsl[idx] = f2bf(v - bf2f(h));
            }
            stage_panel(p.h0[in][0] + (size_t)mt * 16384,
                        p.h0[in][1] + (size_t)mt * 16384, smA_h, smA_l, tid);
            __syncthreads();
            f32x4 acc = (f32x4){0.f, 0.f, 0.f, 0.f};
            const bf16* aH = smA_h + lane * 8;
            const bf16* aL = smA_l + lane * 8;
            const bf16* wha = p.eU0h + (size_t)nt * NKB_H * 512 + lane * 8;
            const bf16* wla = p.eU0l + (size_t)nt * NKB_H * 512 + lane * 8;
            if (role == 0) {
                float bv = p.eb0[nt * 16 + lm];
                acc = (f32x4){bv, bv, bv, bv};
                gemm_lds<32>(xsh + lm * XST + quad * 8, xsl + lm * XST + quad * 8,
                             p.w0h + (size_t)nt * NKB_X * 512 + lane * 8,
                             p.w0l + (size_t)nt * NKB_X * 512 + lane * 8,
                             NKB_X, &acc);
                gemm_lds<512>(aH, aL, wha, wla, 9, &acc);
            } else {
                gemm_lds<512>(aH + 9 * 512, aL + 9 * 512, wha + 9 * 512,
                              wla + 9 * 512, 23, &acc);
                red[tile * 256 + lane * 4 + 0] = acc[0];
                red[tile * 256 + lane * 4 + 1] = acc[1];
                red[tile * 256 + lane * 4 + 2] = acc[2];
                red[tile * 256 + lane * 4 + 3] = acc[3];
            }
            __syncthreads();
            if (role == 0) {
#pragma unroll
                for (int r = 0; r < 4; r++) acc[r] += red[tile * 256 + lane * 4 + r];
            }
            emit_tile(acc, role == 0, tile, lm, quad, sst_h, sst_l);
            flush_tiles(sst_h, sst_l, p.h0[op][0], p.h0[op][1], mt, lidx, tid);
        }
        gbar16(p.flags, mt, lidx, ++ph);
        // ---- enc L1 ----
        phase_rnn2(p.h0[op][0], p.h0[op][1], p.eW1h, p.eW1l,
                   p.h1[in][0], p.h1[in][1], p.eU1h, p.eU1l, p.eb1,
                   p.h1[op][0], p.h1[op][1],
                   smA_h, smA_l, smB_h, smB_l, red, sst_h, sst_l,
                   mt, lidx, nt, tile, role, lane, lm, quad, tid);
        gbar16(p.flags, mt, lidx, ++ph);
    }

    // ------------------------------ decoder -------------------------------
    for (int s = 0; s < ML; s++) {
        const int in = s & 1, op = in ^ 1;
        // ---- dec L0 ----
        {
            stage_panel(p.h0[in][0] + (size_t)mt * 16384,
                        p.h0[in][1] + (size_t)mt * 16384, smA_h, smA_l, tid);
            int tk0 = 0, tk1 = 0, tk2 = 0, tk3 = 0;
            if (role == 0) {
                const int* tp = p.tok + mt * 16 + quad * 4;
                tk0 = (int)(ld_c32(tp + 0) & 63u);
                tk1 = (int)(ld_c32(tp + 1) & 63u);
                tk2 = (int)(ld_c32(tp + 2) & 63u);
                tk3 = (int)(ld_c32(tp + 3) & 63u);
            }
            __syncthreads();
            f32x4 acc = (f32x4){0.f, 0.f, 0.f, 0.f};
            const bf16* aH = smA_h + lane * 8;
            const bf16* aL = smA_l + lane * 8;
            const bf16* wha = p.dU0h + (size_t)nt * NKB_H * 512 + lane * 8;
            const bf16* wla = p.dU0l + (size_t)nt * NKB_H * 512 + lane * 8;
            if (role == 0) {
                gemm_lds<512>(aH, aL, wha, wla, 16, &acc);
            } else {
                gemm_lds<512>(aH + 16 * 512, aL + 16 * 512, wha + 16 * 512,
                              wla + 16 * 512, 16, &acc);
                red[tile * 256 + lane * 4 + 0] = acc[0];
                red[tile * 256 + lane * 4 + 1] = acc[1];
                red[tile * 256 + lane * 4 + 2] = acc[2];
                red[tile * 256 + lane * 4 + 3] = acc[3];
            }
            __syncthreads();
            if (role == 0) {
                const int n = nt * 16 + lm;
                acc[0] += red[tile * 256 + lane * 4 + 0] + p.EP[(size_t)tk0 * Hh + n];
                acc[1] += red[tile * 256 + lane * 4 + 1] + p.EP[(size_t)tk1 * Hh + n];
                acc[2] += red[tile * 256 + lane * 4 + 2] + p.EP[(size_t)tk2 * Hh + n];
                acc[3] += red[tile * 256 + lane * 4 + 3] + p.EP[(size_t)tk3 * Hh + n];
            }
            emit_tile(acc, role == 0, tile, lm, quad, sst_h, sst_l);
            flush_tiles(sst_h, sst_l, p.h0[op][0], p.h0[op][1], mt, lidx, tid);
        }
        gbar16(p.flags, mt, lidx, ++ph);
        // ---- dec L1 ----
        phase_rnn2(p.h0[op][0], p.h0[op][1], p.dW1h, p.dW1l,
                   p.h1[in][0], p.h1[in][1], p.dU1h, p.dU1l, p.db1,
                   p.h1[op][0], p.h1[op][1],
                   smA_h, smA_l, smB_h, smB_l, red, sst_h, sst_l,
                   mt, lidx, nt, tile, role, lane, lm, quad, tid);
        gbar16(p.flags, mt, lidx, ++ph);
        // ---- fc + argmax (blocks lidx 0..3 of each group; fp64 path) ----
        if (lidx < 4) {
            const bf16* h1hi = p.h1[op][0];
            const bf16* h1lo = p.h1[op][1];
            {
                const int r = tid >> 7, k8 = tid & 127;
                const int b = mt * 16 + lidx * 4 + r;
                const size_t id = (((size_t)mt * 32 + (k8 >> 2)) * 64
                                   + (k8 & 3) * 16 + (b & 15)) * 8;
                ull h0v = ld_c64(h1hi + id);
                ull h1v = ld_c64(h1hi + id + 4);
                ull l0v = ld_c64(h1lo + id);
                ull l1v = ld_c64(h1lo + id + 4);
#pragma unroll
                for (int j = 0; j < 4; j++) {
                    hrow[r * 1024 + k8 * 8 + j] =
                        (double)ubf((unsigned)((h0v >> (16 * j)) & 0xffffu))
                      + (double)ubf((unsigned)((l0v >> (16 * j)) & 0xffffu));
                    hrow[r * 1024 + k8 * 8 + 4 + j] =
                        (double)ubf((unsigned)((h1v >> (16 * j)) & 0xffffu))
                      + (double)ubf((unsigned)((l1v >> (16 * j)) & 0xffffu));
                }
            }
            __syncthreads();
            const int r2 = wave >> 1, half = wave & 1, v = lane;
            const int b2 = mt * 16 + lidx * 4 + r2;
            const double* hr = hrow + r2 * 1024 + half * 512;
            const float* wrh = p.fcw + (size_t)v * Hh + half * 512;
            double a0 = 0.0, a1 = 0.0, a2 = 0.0, a3 = 0.0;
            for (int k = 0; k < 512; k += 4) {
                a0 = fma(hr[k + 0], (double)wrh[k + 0], a0);
                a1 = fma(hr[k + 1], (double)wrh[k + 1], a1);
                a2 = fma(hr[k + 2], (double)wrh[k + 2], a2);
                a3 = fma(hr[k + 3], (double)wrh[k + 3], a3);
            }
            double part = (a0 + a1) + (a2 + a3);
            if (half == 1) dred[r2 * 64 + v] = part;
            __syncthreads();
            if (half == 0) {
                double acc = part + dred[r2 * 64 + v] + (double)p.fcb[v];
                p.out[(size_t)b2 * (Vv * ML) + (size_t)v * ML + s] = (float)acc;
                double bvv = acc;
                int bi = v;
#pragma unroll
                for (int st = 1; st < 64; st <<= 1) {
                    double ov = __shfl_xor(bvv, st, 64);
                    int oi = __shfl_xor(bi, st, 64);
                    if (ov > bvv || (ov == bvv && oi < bi)) { bvv = ov; bi = oi; }
                }
                if (v == 0) st_c32(p.tok + b2, (unsigned)bi);
            }
        }
        gbar16(p.flags, mt, lidx, ++ph);
    }

    // ------------- final hidden output (group-local rows) ------------------
    {
        const size_t base = (size_t)Bb * Vv * ML;
        const int b = mt * 16 + lidx;
        const int layer = tid >> 8;          // 0: h0, 1: h1
        const int k0 = (tid & 255) * 4;
        const bf16* ph_ = layer ? p.h1[0][0] : p.h0[0][0];
        const bf16* pl_ = layer ? p.h1[0][1] : p.h0[0][1];
        const size_t id = sidx(b, k0);
        ull vh = ld_c64(ph_ + id);
        ull vl = ld_c64(pl_ + id);
        float* o = p.out + base + (size_t)layer * Bb * Hh + (size_t)b * Hh + k0;
#pragma unroll
        for (int j = 0; j < 4; j++)
            o[j] = ubf((unsigned)((vh >> (16 * j)) & 0xffffu))
                 + ubf((unsigned)((vl >> (16 * j)) & 0xffffu));
    }
}

// ---------------------------------------------------------------------------
extern "C" void kernel_launch(void* const* d_in, const int* in_sizes, int n_in,
                              void* d_out, int out_size, void* d_ws, size_t ws_size,
                              hipStream_t stream) {
    const float* x   = (const float*)d_in[0];
    const float* emb = (const float*)d_in[1];
    const float* eW0 = (const float*)d_in[2];
    const float* eU0 = (const float*)d_in[3];
    const float* eb0 = (const float*)d_in[4];
    const float* eW1 = (const float*)d_in[5];
    const float* eU1 = (const float*)d_in[6];
    const float* eb1 = (const float*)d_in[7];
    const float* dW0 = (const float*)d_in[8];
    const float* dU0 = (const float*)d_in[9];
    const float* db0 = (const float*)d_in[10];
    const float* dW1 = (const float*)d_in[11];
    const float* dU1 = (const float*)d_in[12];
    const float* db1 = (const float*)d_in[13];
    const float* fcw = (const float*)d_in[14];
    const float* fcb = (const float*)d_in[15];
    (void)in_sizes; (void)n_in; (void)out_size; (void)ws_size;

    char* ws = (char*)d_ws;
    const size_t SB = (size_t)Bb * Hh * 2;           // 512 KB state component
    const size_t WPK = (size_t)64 * NKB_H * 512 * 2; // 2 MB packed square comp
    const size_t WPX = (size_t)64 * NKB_X * 512 * 2; // 0.94 MB packed w0 comp
    bf16 *h0c[2][2], *h1c[2][2];
    size_t o = 0;
    for (int c = 0; c < 2; c++) { h0c[0][c] = (bf16*)(ws + o); o += SB; }
    for (int c = 0; c < 2; c++) { h1c[0][c] = (bf16*)(ws + o); o += SB; }
    int* tok = (int*)(ws + o); o += 1024;              // 256 tokens
    unsigned* flags = (unsigned*)(ws + o); o += 256 * 128;  // 128B-strided
    const size_t zero_bytes = o;
    for (int c = 0; c < 2; c++) { h0c[1][c] = (bf16*)(ws + o); o += SB; }
    for (int c = 0; c < 2; c++) { h1c[1][c] = (bf16*)(ws + o); o += SB; }
    float* EP = (float*)(ws + o); o += (size_t)Vv * Hh * 4;
    bf16 *w0p[2];
    for (int c = 0; c < 2; c++) { w0p[c] = (bf16*)(ws + o); o += WPX; }
    bf16 *eU0p[2], *eW1p[2], *eU1p[2], *dU0p[2], *dW1p[2], *dU1p[2];
    for (int c = 0; c < 2; c++) { eU0p[c] = (bf16*)(ws + o); o += WPK; }
    for (int c = 0; c < 2; c++) { eW1p[c] = (bf16*)(ws + o); o += WPK; }
    for (int c = 0; c < 2; c++) { eU1p[c] = (bf16*)(ws + o); o += WPK; }
    for (int c = 0; c < 2; c++) { dU0p[c] = (bf16*)(ws + o); o += WPK; }
    for (int c = 0; c < 2; c++) { dW1p[c] = (bf16*)(ws + o); o += WPK; }
    for (int c = 0; c < 2; c++) { dU1p[c] = (bf16*)(ws + o); o += WPK; }

    hipMemsetAsync(ws, 0, zero_bytes, stream);
    dim3 blk(256);
    const int GSQ = 64 * NKB_H * 64 / 256;   // 512 blocks
    const int GX  = 64 * NKB_X * 64 / 256;   // 240 blocks
    pack_w_k<<<dim3(GX),  blk, 0, stream>>>(eW0, w0p[0],  w0p[1],  NKB_X, LIN, LIN);
    pack_w_k<<<dim3(GSQ), blk, 0, stream>>>(eU0, eU0p[0], eU0p[1], NKB_H, Hh, Hh);
    pack_w_k<<<dim3(GSQ), blk, 0, stream>>>(eW1, eW1p[0], eW1p[1], NKB_H, Hh, Hh);
    pack_w_k<<<dim3(GSQ), blk, 0, stream>>>(eU1, eU1p[0], eU1p[1], NKB_H, Hh, Hh);
    pack_w_k<<<dim3(GSQ), blk, 0, stream>>>(dU0, dU0p[0], dU0p[1], NKB_H, Hh, Hh);
    pack_w_k<<<dim3(GSQ), blk, 0, stream>>>(dW1, dW1p[0], dW1p[1], NKB_H, Hh, Hh);
    pack_w_k<<<dim3(GSQ), blk, 0, stream>>>(dU1, dU1p[0], dU1p[1], NKB_H, Hh, Hh);
    dec_pre_k<<<dim3(Hh / 256, Vv / 4), blk, 0, stream>>>(emb, dW0, db0, EP);

    Params pr;
    pr.x = x;
    pr.w0h = w0p[0];  pr.w0l = w0p[1];
    pr.eU0h = eU0p[0]; pr.eU0l = eU0p[1];
    pr.eW1h = eW1p[0]; pr.eW1l = eW1p[1];
    pr.eU1h = eU1p[0]; pr.eU1l = eU1p[1];
    pr.dU0h = dU0p[0]; pr.dU0l = dU0p[1];
    pr.dW1h = dW1p[0]; pr.dW1l = dW1p[1];
    pr.dU1h = dU1p[0]; pr.dU1l = dU1p[1];
    pr.eb0 = eb0; pr.eb1 = eb1; pr.db1 = db1;
    pr.EP = EP; pr.fcw = fcw; pr.fcb = fcb;
    pr.out = (float*)d_out;
    pr.tok = tok;
    for (int pp = 0; pp < 2; pp++)
        for (int c = 0; c < 2; c++) {
            pr.h0[pp][c] = h0c[pp][c];
            pr.h1[pp][c] = h1c[pp][c];
        }
    pr.flags = flags;

    void* kargs[] = { (void*)&pr };
    hipLaunchCooperativeKernel((void*)persist_k, dim3(NBLK), dim3(NTHR),
                               kargs, 0, stream);
}